// Round 1
// baseline (1637.708 us; speedup 1.0000x reference)
//
#include <hip/hip_runtime.h>
#include <hip/hip_bf16.h>
#include <cstdint>
#include <cstddef>

#define DEVINL __device__ __forceinline__

typedef _Float16 f16x8 __attribute__((ext_vector_type(8)));
typedef _Float16 f16x2 __attribute__((ext_vector_type(2)));
typedef float    f32x4 __attribute__((ext_vector_type(4)));

// B=4, T=256, U=64, E=H=J=512, O=1024, gate rows 2048

DEVINL float fsigm(float x) {
    float e = __expf(-x);
    return __builtin_amdgcn_rcpf(1.f + e);
}
DEVINL float ftanh(float x) {
    float e = __expf(2.f * x);
    return 1.f - 2.f * __builtin_amdgcn_rcpf(e + 1.f);
}

DEVINL float dot8(f16x8 w, f16x8 x, float acc) {
    f16x2 w0{w[0], w[1]}, w1{w[2], w[3]}, w2{w[4], w[5]}, w3{w[6], w[7]};
    f16x2 x0{x[0], x[1]}, x1{x[2], x[3]}, x2{x[4], x[5]}, x3{x[6], x[7]};
    acc = __builtin_amdgcn_fdot2(w0, x0, acc, false);
    acc = __builtin_amdgcn_fdot2(w1, x1, acc, false);
    acc = __builtin_amdgcn_fdot2(w2, x2, acc, false);
    acc = __builtin_amdgcn_fdot2(w3, x3, acc, false);
    return acc;
}

// ---------------------------------------------------------------------------
// prep: cast LSTM weights + W_out to f16
// dst layout (elements): [Wih0 1M | Whh0 1M | Wih1 1M | Whh1 1M | Wout 0.5M]
// ---------------------------------------------------------------------------
__global__ void k_prep_f16(const float* __restrict__ wih0, const float* __restrict__ whh0,
                           const float* __restrict__ wih1, const float* __restrict__ whh1,
                           const float* __restrict__ wout, _Float16* __restrict__ dst, int total) {
    int stride = gridDim.x * blockDim.x;
    for (int i = blockIdx.x * blockDim.x + threadIdx.x; i < total; i += stride) {
        const float* src; int off;
        if      (i < (1 << 20)) { src = wih0; off = i; }
        else if (i < (2 << 20)) { src = whh0; off = i - (1 << 20); }
        else if (i < (3 << 20)) { src = wih1; off = i - (2 << 20); }
        else if (i < (4 << 20)) { src = whh1; off = i - (3 << 20); }
        else                    { src = wout; off = i - (4 << 20); }
        dst[i] = (_Float16)src[off];
    }
}

// ---------------------------------------------------------------------------
// embedding gather (f16 output): Ebuf[(u*4+b)*512 + e] = embed[ys_in[b][u]][e]
// ---------------------------------------------------------------------------
__global__ void k_embed(const float* __restrict__ embed, const int* __restrict__ ys,
                        _Float16* __restrict__ Ebuf) {
    int bu = blockIdx.x;           // 0..255
    int b = bu >> 6, u = bu & 63;
    int tok = (u == 0) ? 0 : ys[b * 63 + (u - 1)];
    const float* src = embed + (size_t)tok * 512;
    _Float16* dst = Ebuf + ((size_t)(u * 4 + b)) * 512;
    int t2 = threadIdx.x * 2;
    float2 v = *(const float2*)(src + t2);
    dst[t2]     = (_Float16)v.x;
    dst[t2 + 1] = (_Float16)v.y;
}

// ---------------------------------------------------------------------------
// persistent 2-layer LSTM. 64 blocks x 256 threads.
// blocks 0..31: layer0, 32..63: layer1 (lagging one round).
// Block owns 16 hidden units -> 64 gate rows x 4 batches.
//
// v2 design:
//  * All weights (Wih + Whh rows for the block) live in VGPRs: thread
//    (rg=tid>>5, kp=tid&31) holds 8 rows (rb=rg*8..rg*8+7) x two 8-f16
//    chunks per 512-seg at k = kp*8 and 256+kp*8.  128 VGPRs, loaded once.
//  * h exchanged as f16 via 8B relaxed agent atomics (history-indexed
//    buffers H0h/H1h, so layer0 can free-run ahead of layer1).
//  * Per-layer flags: layer0 polls only flags[0..31]; layer1 polls its own
//    32 first (hh dots overlap the L0 wait), then flags[0..31] for H0[st].
//  * Layer0's x-side dots (static Ebuf) run BEFORE its flag wait.
//  * Cross-kp reduction: butterfly reduce-scatter over the 32 kp lanes
//    (31 __shfl_xor), lane kp ends owning gate cell t=kp -> (row rg*8+(kp>>2),
//    batch kp&3).  No LDS partial buffer.
// ---------------------------------------------------------------------------
__global__ void __launch_bounds__(256, 1) k_lstm(
        const _Float16* __restrict__ WF,
        const float* __restrict__ bih0, const float* __restrict__ bhh0,
        const float* __restrict__ bih1, const float* __restrict__ bhh1,
        const _Float16* __restrict__ Ebuf,
        _Float16* __restrict__ H0h, _Float16* __restrict__ H1h,
        float* __restrict__ H1, int* __restrict__ flags) {
    const int blk   = blockIdx.x;
    const int layer = blk >> 5;
    const int ublk  = blk & 31;
    const int unit0 = ublk * 16;
    const int tid   = threadIdx.x;
    const int rg    = tid >> 5;          // 0..7 : row group (8 rows)
    const int kp    = tid & 31;          // 0..31: k phase

    // cell owned after reduce-scatter
    const int rb_own   = rg * 8 + (kp >> 2);                 // 0..63
    const int b_own    = kp & 3;
    const int grow_own = ((rb_own >> 4) << 9) + unit0 + (rb_own & 15);

    const _Float16* WihL = WF + (size_t)(layer ? (2u << 20) : 0u);
    const _Float16* WhhL = WF + (size_t)(layer ? (3u << 20) : (1u << 20));

    // ---- persistent weights in VGPRs ----
    f16x8 wA[8][2];   // Wih rows
    f16x8 wB[8][2];   // Whh rows
    #pragma unroll
    for (int r = 0; r < 8; ++r) {
        int rb = rg * 8 + r;
        int grow = ((rb >> 4) << 9) + unit0 + (rb & 15);
        const _Float16* irow = WihL + (size_t)grow * 512;
        const _Float16* hrow = WhhL + (size_t)grow * 512;
        wA[r][0] = *(const f16x8*)(irow + kp * 8);
        wA[r][1] = *(const f16x8*)(irow + 256 + kp * 8);
        wB[r][0] = *(const f16x8*)(hrow + kp * 8);
        wB[r][1] = *(const f16x8*)(hrow + 256 + kp * 8);
    }
    const float* biL = layer ? bih1 : bih0;
    const float* bhL = layer ? bhh1 : bhh0;
    const float bsum = biL[grow_own] + bhL[grow_own];

    __shared__ _Float16 xh_x[4 * 512];   // x-half, f16, [b][512] linear
    __shared__ _Float16 xh_h[4 * 512];   // h-half
    __shared__ float g_lds[64 * 4];      // gates [rb][b]

    float c_reg = 0.f;
    const int fb   = layer ? 32 : 0;
    const int s_lo = layer ? 1 : 0;
    const int s_hi = layer ? 64 : 63;

    for (int s = s_lo; s <= s_hi; ++s) {
        const int st = s - s_lo;         // L0: st=s ; L1: st=s-1

        float p[8][4];
        #pragma unroll
        for (int r = 0; r < 8; ++r)
            #pragma unroll
            for (int b = 0; b < 4; ++b) p[r][b] = 0.f;

        if (!layer) {
            // ---- x-half is static (Ebuf): stage + ih dots BEFORE the wait ----
            {
                f16x8 ev = *(const f16x8*)(Ebuf + (size_t)st * 2048 + tid * 8);
                *(f16x8*)(xh_x + tid * 8) = ev;
            }
            __syncthreads();
            #pragma unroll
            for (int b = 0; b < 4; ++b) {
                f16x8 xA = *(const f16x8*)(xh_x + b * 512 + kp * 8);
                f16x8 xB = *(const f16x8*)(xh_x + b * 512 + 256 + kp * 8);
                #pragma unroll
                for (int r = 0; r < 8; ++r) {
                    p[r][b] = dot8(wA[r][0], xA, p[r][b]);
                    p[r][b] = dot8(wA[r][1], xB, p[r][b]);
                }
            }
            // ---- wait own group (peers finished round s-1) ----
            if (s > 0) {
                if (tid < 32) {
                    for (;;) {
                        int f = __hip_atomic_load(flags + tid * 16, __ATOMIC_ACQUIRE,
                                                  __HIP_MEMORY_SCOPE_AGENT);
                        if (__ballot(f < s) == 0ull) break;
                        __builtin_amdgcn_s_sleep(1);
                    }
                }
                __syncthreads();
            }
            // ---- stage h0[st-1] (f16, 8B atomics) ----
            {
                uint64_t v0 = 0, v1 = 0;
                if (st > 0) {
                    const uint64_t* p64 = (const uint64_t*)(H0h + (size_t)(st - 1) * 2048) + tid * 2;
                    v0 = __hip_atomic_load(p64,     __ATOMIC_RELAXED, __HIP_MEMORY_SCOPE_AGENT);
                    v1 = __hip_atomic_load(p64 + 1, __ATOMIC_RELAXED, __HIP_MEMORY_SCOPE_AGENT);
                }
                *(uint64_t*)(xh_h + tid * 8)     = v0;
                *(uint64_t*)(xh_h + tid * 8 + 4) = v1;
            }
            __syncthreads();
            #pragma unroll
            for (int b = 0; b < 4; ++b) {
                f16x8 hA = *(const f16x8*)(xh_h + b * 512 + kp * 8);
                f16x8 hB = *(const f16x8*)(xh_h + b * 512 + 256 + kp * 8);
                #pragma unroll
                for (int r = 0; r < 8; ++r) {
                    p[r][b] = dot8(wB[r][0], hA, p[r][b]);
                    p[r][b] = dot8(wB[r][1], hB, p[r][b]);
                }
            }
        } else {
            // ---- wait own group, stage h1[st-1], hh dots (overlaps L0) ----
            if (s > 1) {
                if (tid < 32) {
                    for (;;) {
                        int f = __hip_atomic_load(flags + (fb + tid) * 16, __ATOMIC_ACQUIRE,
                                                  __HIP_MEMORY_SCOPE_AGENT);
                        if (__ballot(f < s) == 0ull) break;
                        __builtin_amdgcn_s_sleep(1);
                    }
                }
                __syncthreads();
            }
            {
                uint64_t v0 = 0, v1 = 0;
                if (st > 0) {
                    const uint64_t* p64 = (const uint64_t*)(H1h + (size_t)(st - 1) * 2048) + tid * 2;
                    v0 = __hip_atomic_load(p64,     __ATOMIC_RELAXED, __HIP_MEMORY_SCOPE_AGENT);
                    v1 = __hip_atomic_load(p64 + 1, __ATOMIC_RELAXED, __HIP_MEMORY_SCOPE_AGENT);
                }
                *(uint64_t*)(xh_h + tid * 8)     = v0;
                *(uint64_t*)(xh_h + tid * 8 + 4) = v1;
            }
            __syncthreads();
            #pragma unroll
            for (int b = 0; b < 4; ++b) {
                f16x8 hA = *(const f16x8*)(xh_h + b * 512 + kp * 8);
                f16x8 hB = *(const f16x8*)(xh_h + b * 512 + 256 + kp * 8);
                #pragma unroll
                for (int r = 0; r < 8; ++r) {
                    p[r][b] = dot8(wB[r][0], hA, p[r][b]);
                    p[r][b] = dot8(wB[r][1], hB, p[r][b]);
                }
            }
            // ---- wait layer0 >= s (H0[st] ready), stage x = h0[st], ih dots ----
            if (tid < 32) {
                for (;;) {
                    int f = __hip_atomic_load(flags + tid * 16, __ATOMIC_ACQUIRE,
                                              __HIP_MEMORY_SCOPE_AGENT);
                    if (__ballot(f < s) == 0ull) break;
                    __builtin_amdgcn_s_sleep(1);
                }
            }
            __syncthreads();
            {
                const uint64_t* p64 = (const uint64_t*)(H0h + (size_t)st * 2048) + tid * 2;
                uint64_t v0 = __hip_atomic_load(p64,     __ATOMIC_RELAXED, __HIP_MEMORY_SCOPE_AGENT);
                uint64_t v1 = __hip_atomic_load(p64 + 1, __ATOMIC_RELAXED, __HIP_MEMORY_SCOPE_AGENT);
                *(uint64_t*)(xh_x + tid * 8)     = v0;
                *(uint64_t*)(xh_x + tid * 8 + 4) = v1;
            }
            __syncthreads();
            #pragma unroll
            for (int b = 0; b < 4; ++b) {
                f16x8 xA = *(const f16x8*)(xh_x + b * 512 + kp * 8);
                f16x8 xB = *(const f16x8*)(xh_x + b * 512 + 256 + kp * 8);
                #pragma unroll
                for (int r = 0; r < 8; ++r) {
                    p[r][b] = dot8(wA[r][0], xA, p[r][b]);
                    p[r][b] = dot8(wA[r][1], xB, p[r][b]);
                }
            }
        }

        // ---- butterfly reduce-scatter over 32 kp lanes: lane kp owns t=kp ----
        float a[32];
        #pragma unroll
        for (int t = 0; t < 32; ++t) a[t] = p[t >> 2][t & 3];
        #pragma unroll
        for (int m = 16; m >= 1; m >>= 1) {
            const bool hi = (kp & m) != 0;
            #pragma unroll
            for (int i = 0; i < m; ++i) {
                float give = hi ? a[i] : a[i + m];
                float got  = __shfl_xor(give, m, 64);
                a[i] = (hi ? a[i + m] : a[i]) + got;
            }
        }
        g_lds[rb_own * 4 + b_own] = a[0] + bsum;
        __syncthreads();

        // ---- activations + h/c update (wave 0 only) ----
        if (tid < 64) {
            int jj = tid >> 2, b4 = tid & 3;
            float gi = g_lds[(0  + jj) * 4 + b4];
            float gf = g_lds[(16 + jj) * 4 + b4];
            float gg = g_lds[(32 + jj) * 4 + b4];
            float go = g_lds[(48 + jj) * 4 + b4];
            c_reg = fsigm(gf) * c_reg + fsigm(gi) * ftanh(gg);
            float h2 = fsigm(go) * ftanh(c_reg);
            int hu = unit0 + jj;
            _Float16 h16 = (_Float16)h2;
            short hb;
            __builtin_memcpy(&hb, &h16, 2);
            if (!layer) {
                __hip_atomic_store((short*)(H0h + (size_t)((st << 2) + b4) * 512 + hu), hb,
                                   __ATOMIC_RELAXED, __HIP_MEMORY_SCOPE_AGENT);
            } else {
                __hip_atomic_store((short*)(H1h + (size_t)((st << 2) + b4) * 512 + hu), hb,
                                   __ATOMIC_RELAXED, __HIP_MEMORY_SCOPE_AGENT);
                __hip_atomic_store(H1 + ((size_t)(b4 * 64 + st)) * 512 + hu, h2,
                                   __ATOMIC_RELAXED, __HIP_MEMORY_SCOPE_AGENT);
            }
        }
        // flag release: all h stores are wave-0 stores; the release fence
        // (vmcnt drain) covers them.  Next round's top barrier separates
        // LDS reuse, so no block-wide barrier needed here.
        if (tid == 0)
            __hip_atomic_store(flags + blk * 16, s + 1, __ATOMIC_RELEASE,
                               __HIP_MEMORY_SCOPE_AGENT);
    }
}

// ---------------------------------------------------------------------------
// small fp32 GEMM: C[m][n] = bias[n] + sum_k A[m][k]*Bt[n][k];  N=K=512.
// 64x64 tile per block; grid.x = (M/64)*8
// ---------------------------------------------------------------------------
__global__ void __launch_bounds__(256) k_gemm_small(
        const float* __restrict__ A, const float* __restrict__ Bt,
        const float* __restrict__ bias, float* __restrict__ C) {
    __shared__ float As[64 * 68];
    __shared__ float Bs[64 * 68];
    int bn = blockIdx.x & 7;
    int bm = blockIdx.x >> 3;
    int m0 = bm * 64, n0 = bn * 64;
    int tid = threadIdx.x;
    int tx = tid & 15, ty = tid >> 4;
    float acc[4][4] = {};
    for (int k0 = 0; k0 < 512; k0 += 64) {
        __syncthreads();
        #pragma unroll
        for (int i = 0; i < 4; ++i) {
            int fid = i * 256 + tid;
            int rr = fid >> 4, c4 = (fid & 15) * 4;
            *(float4*)(As + rr * 68 + c4) = *(const float4*)(A + (size_t)(m0 + rr) * 512 + k0 + c4);
            *(float4*)(Bs + rr * 68 + c4) = *(const float4*)(Bt + (size_t)(n0 + rr) * 512 + k0 + c4);
        }
        __syncthreads();
        #pragma unroll 4
        for (int kk = 0; kk < 64; kk += 4) {
            float4 a4[4], b4[4];
            #pragma unroll
            for (int ii = 0; ii < 4; ++ii) a4[ii] = *(const float4*)(As + (ty + ii * 16) * 68 + kk);
            #pragma unroll
            for (int jjx = 0; jjx < 4; ++jjx) b4[jjx] = *(const float4*)(Bs + (tx + jjx * 16) * 68 + kk);
            #pragma unroll
            for (int ii = 0; ii < 4; ++ii)
                #pragma unroll
                for (int jjx = 0; jjx < 4; ++jjx)
                    acc[ii][jjx] += a4[ii].x * b4[jjx].x + a4[ii].y * b4[jjx].y +
                                    a4[ii].z * b4[jjx].z + a4[ii].w * b4[jjx].w;
        }
    }
    #pragma unroll
    for (int ii = 0; ii < 4; ++ii) {
        int m = m0 + ty + ii * 16;
        #pragma unroll
        for (int jjx = 0; jjx < 4; ++jjx) {
            int n = n0 + tx + jjx * 16;
            float v = acc[ii][jjx] + (bias ? bias[n] : 0.f);
            C[(size_t)m * 512 + n] = v;
        }
    }
}

// ---------------------------------------------------------------------------
// joint: out[m][n] = b_out[n] + sum_k tanh(henc[b,t,k]+hdec[b,u,k]) * Wo[n][k]
// m = b*16384 + t*64 + u; M=65536, N=1024, K=512.
// 128x128 tile, BK=64, f16 MFMA 16x16x32, 4 waves 2x2, 4x4 accs each.
// ---------------------------------------------------------------------------
__global__ void __launch_bounds__(256) k_joint(
        const float* __restrict__ henc, const float* __restrict__ hdec,
        const _Float16* __restrict__ Wo, const float* __restrict__ b_out,
        float* __restrict__ out) {
    __shared__ _Float16 As[128 * 72];
    __shared__ _Float16 Bs[128 * 72];

    const int bn = blockIdx.x & 7;
    const int bm = blockIdx.x >> 3;
    const int m0 = bm * 128, n0 = bn * 128;
    const int b  = m0 >> 14;
    const int t0 = (m0 & 16383) >> 6;

    const int tid  = threadIdx.x;
    const int wave = tid >> 6, lane = tid & 63;
    const int wm = wave >> 1, wn = wave & 1;
    const int l16 = lane & 15, quad = lane >> 4;

    const int r_gen = tid >> 1;
    const int half  = tid & 1;
    const int tg = r_gen >> 6, ug = r_gen & 63;
    const float* he_row = henc + ((size_t)(b * 256 + t0 + tg)) * 512 + half * 32;
    const float* hd_row = hdec + ((size_t)(b * 64 + ug)) * 512 + half * 32;
    _Float16* As_row = As + r_gen * 72 + half * 32;

    f32x4 acc[4][4];
    #pragma unroll
    for (int i = 0; i < 4; ++i)
        #pragma unroll
        for (int jx = 0; jx < 4; ++jx) acc[i][jx] = f32x4{0.f, 0.f, 0.f, 0.f};

    for (int kit = 0; kit < 8; ++kit) {
        const int k0 = kit * 64;
        __syncthreads();
        #pragma unroll
        for (int i2 = 0; i2 < 4; ++i2) {
            float4 a  = *(const float4*)(he_row + k0 + i2 * 8);
            float4 c  = *(const float4*)(hd_row + k0 + i2 * 8);
            float4 a2 = *(const float4*)(he_row + k0 + i2 * 8 + 4);
            float4 c2 = *(const float4*)(hd_row + k0 + i2 * 8 + 4);
            f16x8 z8;
            z8[0] = (_Float16)ftanh(a.x + c.x);
            z8[1] = (_Float16)ftanh(a.y + c.y);
            z8[2] = (_Float16)ftanh(a.z + c.z);
            z8[3] = (_Float16)ftanh(a.w + c.w);
            z8[4] = (_Float16)ftanh(a2.x + c2.x);
            z8[5] = (_Float16)ftanh(a2.y + c2.y);
            z8[6] = (_Float16)ftanh(a2.z + c2.z);
            z8[7] = (_Float16)ftanh(a2.w + c2.w);
            *(f16x8*)(As_row + i2 * 8) = z8;
        }
        #pragma unroll
        for (int j2 = 0; j2 < 4; ++j2) {
            int q = j2 * 256 + tid;
            int rr = q >> 3, c8 = q & 7;
            f16x8 w = *(const f16x8*)(Wo + (size_t)(n0 + rr) * 512 + k0 + c8 * 8);
            *(f16x8*)(Bs + rr * 72 + c8 * 8) = w;
        }
        __syncthreads();
        #pragma unroll
        for (int kk = 0; kk < 64; kk += 32) {
            f16x8 af[4], bfv[4];
            #pragma unroll
            for (int i = 0; i < 4; ++i)
                af[i] = *(const f16x8*)(As + (wm * 64 + i * 16 + l16) * 72 + kk + quad * 8);
            #pragma unroll
            for (int jx = 0; jx < 4; ++jx)
                bfv[jx] = *(const f16x8*)(Bs + (wn * 64 + jx * 16 + l16) * 72 + kk + quad * 8);
            #pragma unroll
            for (int i = 0; i < 4; ++i)
                #pragma unroll
                for (int jx = 0; jx < 4; ++jx)
                    acc[i][jx] = __builtin_amdgcn_mfma_f32_16x16x32_f16(af[i], bfv[jx], acc[i][jx], 0, 0, 0);
        }
    }
    #pragma unroll
    for (int i = 0; i < 4; ++i) {
        int mrow = m0 + wm * 64 + i * 16 + quad * 4;
        #pragma unroll
        for (int jx = 0; jx < 4; ++jx) {
            int col = n0 + wn * 64 + jx * 16 + l16;
            float bo = b_out[col];
            float* po = out + (size_t)mrow * 1024 + col;
            po[0]    = acc[i][jx][0] + bo;
            po[1024] = acc[i][jx][1] + bo;
            po[2048] = acc[i][jx][2] + bo;
            po[3072] = acc[i][jx][3] + bo;
        }
    }
}

// ---------------------------------------------------------------------------
extern "C" void kernel_launch(void* const* d_in, const int* in_sizes, int n_in,
                              void* d_out, int out_size, void* d_ws, size_t ws_size,
                              hipStream_t stream) {
    const float* hs    = (const float*)d_in[0];
    const int*   ys    = (const int*)d_in[2];
    const float* embed = (const float*)d_in[3];
    const float* wih0  = (const float*)d_in[4];
    const float* whh0  = (const float*)d_in[5];
    const float* bih0  = (const float*)d_in[6];
    const float* bhh0  = (const float*)d_in[7];
    const float* wih1  = (const float*)d_in[8];
    const float* whh1  = (const float*)d_in[9];
    const float* bih1  = (const float*)d_in[10];
    const float* bhh1  = (const float*)d_in[11];
    const float* wenc  = (const float*)d_in[12];
    const float* benc  = (const float*)d_in[13];
    const float* wdec  = (const float*)d_in[14];
    const float* wout  = (const float*)d_in[15];
    const float* bout  = (const float*)d_in[16];
    float* out = (float*)d_out;

    char* ws = (char*)d_ws;
    _Float16* WF     = (_Float16*)(ws);                               // 9 MB
    _Float16* Ebuf16 = (_Float16*)(ws + 9u  * 1024 * 1024);           // 256 KB
    _Float16* H0h    = (_Float16*)(ws + 9u  * 1024 * 1024 + 512u * 1024); // 256 KB f16
    _Float16* H1h    = (_Float16*)(ws + 9u  * 1024 * 1024 + 768u * 1024); // 256 KB f16
    float* H1    = (float*)(ws + 10u * 1024 * 1024);                  // 512 KB
    float* henc  = (float*)(ws + 10u * 1024 * 1024 + 512u * 1024);    // 2 MB
    float* hdec  = (float*)(ws + 12u * 1024 * 1024 + 512u * 1024);    // 512 KB
    int*   flags = (int*)  (ws + 13u * 1024 * 1024);                  // 4 KB

    hipMemsetAsync(flags, 0, 64 * 16 * sizeof(int), stream);
    k_prep_f16<<<2048, 256, 0, stream>>>(wih0, whh0, wih1, whh1, wout, WF, 4718592);
    k_embed<<<256, 256, 0, stream>>>(embed, ys, Ebuf16);
    k_lstm<<<64, 256, 0, stream>>>(WF, bih0, bhh0, bih1, bhh1, Ebuf16, H0h, H1h, H1, flags);
    k_gemm_small<<<128, 256, 0, stream>>>(hs, wenc, benc, henc);      // M=1024
    k_gemm_small<<<32, 256, 0, stream>>>(H1, wdec, nullptr, hdec);    // M=256
    k_joint<<<4096, 256, 0, stream>>>(henc, hdec, WF + (4u << 20), bout, out);
}

// Round 2
// 1624.918 us; speedup vs baseline: 1.0079x; 1.0079x over previous
//
#include <hip/hip_runtime.h>
#include <hip/hip_bf16.h>
#include <cstdint>
#include <cstddef>

#define DEVINL __device__ __forceinline__

typedef _Float16 f16x8 __attribute__((ext_vector_type(8)));
typedef _Float16 f16x2 __attribute__((ext_vector_type(2)));
typedef float    f32x4 __attribute__((ext_vector_type(4)));

// B=4, T=256, U=64, E=H=J=512, O=1024, gate rows 2048

DEVINL float fsigm(float x) {
    float e = __expf(-x);
    return __builtin_amdgcn_rcpf(1.f + e);
}
DEVINL float ftanh(float x) {
    float e = __expf(2.f * x);
    return 1.f - 2.f * __builtin_amdgcn_rcpf(e + 1.f);
}

DEVINL float dot8(f16x8 w, f16x8 x, float acc) {
    f16x2 w0{w[0], w[1]}, w1{w[2], w[3]}, w2{w[4], w[5]}, w3{w[6], w[7]};
    f16x2 x0{x[0], x[1]}, x1{x[2], x[3]}, x2{x[4], x[5]}, x3{x[6], x[7]};
    acc = __builtin_amdgcn_fdot2(w0, x0, acc, false);
    acc = __builtin_amdgcn_fdot2(w1, x1, acc, false);
    acc = __builtin_amdgcn_fdot2(w2, x2, acc, false);
    acc = __builtin_amdgcn_fdot2(w3, x3, acc, false);
    return acc;
}

// ---------------------------------------------------------------------------
// prep: cast LSTM weights + W_out to f16
// dst layout (elements): [Wih0 1M | Whh0 1M | Wih1 1M | Whh1 1M | Wout 0.5M]
// ---------------------------------------------------------------------------
__global__ void k_prep_f16(const float* __restrict__ wih0, const float* __restrict__ whh0,
                           const float* __restrict__ wih1, const float* __restrict__ whh1,
                           const float* __restrict__ wout, _Float16* __restrict__ dst, int total) {
    int stride = gridDim.x * blockDim.x;
    for (int i = blockIdx.x * blockDim.x + threadIdx.x; i < total; i += stride) {
        const float* src; int off;
        if      (i < (1 << 20)) { src = wih0; off = i; }
        else if (i < (2 << 20)) { src = whh0; off = i - (1 << 20); }
        else if (i < (3 << 20)) { src = wih1; off = i - (2 << 20); }
        else if (i < (4 << 20)) { src = whh1; off = i - (3 << 20); }
        else                    { src = wout; off = i - (4 << 20); }
        dst[i] = (_Float16)src[off];
    }
}

// ---------------------------------------------------------------------------
// embedding gather (f16 output): Ebuf[(u*4+b)*512 + e] = embed[ys_in[b][u]][e]
// ---------------------------------------------------------------------------
__global__ void k_embed(const float* __restrict__ embed, const int* __restrict__ ys,
                        _Float16* __restrict__ Ebuf) {
    int bu = blockIdx.x;           // 0..255
    int b = bu >> 6, u = bu & 63;
    int tok = (u == 0) ? 0 : ys[b * 63 + (u - 1)];
    const float* src = embed + (size_t)tok * 512;
    _Float16* dst = Ebuf + ((size_t)(u * 4 + b)) * 512;
    int t2 = threadIdx.x * 2;
    float2 v = *(const float2*)(src + t2);
    dst[t2]     = (_Float16)v.x;
    dst[t2 + 1] = (_Float16)v.y;
}

// ---------------------------------------------------------------------------
// persistent 2-layer LSTM. 64 blocks x 256 threads.
// blocks 0..31: layer0, 32..63: layer1 (lagging one round).
// Block owns 16 hidden units -> 64 gate rows x 4 batches.
//
// v3 sync design (the v2 regression root-cause):
//  * ALL cross-block payload moves via relaxed agent-scope atomics, which
//    bypass the non-coherent L1/L2 and read/write the coherence point
//    directly. So the flag polls DO NOT need acquire (acquire emits an
//    L2-invalidate per poll iteration -> invalidate storm, the v1/v2 cost),
//    and the flag release does not need an L2 writeback: a relaxed store
//    preceded by s_waitcnt vmcnt(0) gives store->store ordering at the LLC.
//  * Weights persistent in VGPRs (128 VGPR/thread), butterfly reduce-scatter,
//    f16 h exchange, per-layer flags, L0 free-runs (history-indexed H0h).
// ---------------------------------------------------------------------------
__global__ void __launch_bounds__(256, 1) k_lstm(
        const _Float16* __restrict__ WF,
        const float* __restrict__ bih0, const float* __restrict__ bhh0,
        const float* __restrict__ bih1, const float* __restrict__ bhh1,
        const _Float16* __restrict__ Ebuf,
        _Float16* __restrict__ H0h, _Float16* __restrict__ H1h,
        float* __restrict__ H1, int* __restrict__ flags) {
    const int blk   = blockIdx.x;
    const int layer = blk >> 5;
    const int ublk  = blk & 31;
    const int unit0 = ublk * 16;
    const int tid   = threadIdx.x;
    const int rg    = tid >> 5;          // 0..7 : row group (8 rows)
    const int kp    = tid & 31;          // 0..31: k phase

    // cell owned after reduce-scatter
    const int rb_own   = rg * 8 + (kp >> 2);                 // 0..63
    const int b_own    = kp & 3;
    const int grow_own = ((rb_own >> 4) << 9) + unit0 + (rb_own & 15);

    const _Float16* WihL = WF + (size_t)(layer ? (2u << 20) : 0u);
    const _Float16* WhhL = WF + (size_t)(layer ? (3u << 20) : (1u << 20));

    // ---- persistent weights in VGPRs ----
    f16x8 wA[8][2];   // Wih rows
    f16x8 wB[8][2];   // Whh rows
    #pragma unroll
    for (int r = 0; r < 8; ++r) {
        int rb = rg * 8 + r;
        int grow = ((rb >> 4) << 9) + unit0 + (rb & 15);
        const _Float16* irow = WihL + (size_t)grow * 512;
        const _Float16* hrow = WhhL + (size_t)grow * 512;
        wA[r][0] = *(const f16x8*)(irow + kp * 8);
        wA[r][1] = *(const f16x8*)(irow + 256 + kp * 8);
        wB[r][0] = *(const f16x8*)(hrow + kp * 8);
        wB[r][1] = *(const f16x8*)(hrow + 256 + kp * 8);
    }
    const float* biL = layer ? bih1 : bih0;
    const float* bhL = layer ? bhh1 : bhh0;
    const float bsum = biL[grow_own] + bhL[grow_own];

    __shared__ _Float16 xh_x[4 * 512];   // x-half, f16, [b][512] linear
    __shared__ _Float16 xh_h[4 * 512];   // h-half
    __shared__ float g_lds[64 * 4];      // gates [rb][b]

    float c_reg = 0.f;
    const int fb   = layer ? 32 : 0;
    const int s_lo = layer ? 1 : 0;
    const int s_hi = layer ? 64 : 63;

    for (int s = s_lo; s <= s_hi; ++s) {
        const int st = s - s_lo;         // L0: st=s ; L1: st=s-1

        float p[8][4];
        #pragma unroll
        for (int r = 0; r < 8; ++r)
            #pragma unroll
            for (int b = 0; b < 4; ++b) p[r][b] = 0.f;

        if (!layer) {
            // ---- x-half is static (Ebuf): stage + ih dots BEFORE the wait ----
            {
                f16x8 ev = *(const f16x8*)(Ebuf + (size_t)st * 2048 + tid * 8);
                *(f16x8*)(xh_x + tid * 8) = ev;
            }
            __syncthreads();
            #pragma unroll
            for (int b = 0; b < 4; ++b) {
                f16x8 xA = *(const f16x8*)(xh_x + b * 512 + kp * 8);
                f16x8 xB = *(const f16x8*)(xh_x + b * 512 + 256 + kp * 8);
                #pragma unroll
                for (int r = 0; r < 8; ++r) {
                    p[r][b] = dot8(wA[r][0], xA, p[r][b]);
                    p[r][b] = dot8(wA[r][1], xB, p[r][b]);
                }
            }
            // ---- wait own group (peers finished round s-1); RELAXED poll ----
            if (s > 0) {
                if (tid < 32) {
                    for (;;) {
                        int f = __hip_atomic_load(flags + tid * 16, __ATOMIC_RELAXED,
                                                  __HIP_MEMORY_SCOPE_AGENT);
                        if (__ballot(f < s) == 0ull) break;
                        __builtin_amdgcn_s_sleep(1);
                    }
                }
                __syncthreads();
            }
            // ---- stage h0[st-1] (f16, 8B relaxed agent atomics) ----
            {
                uint64_t v0 = 0, v1 = 0;
                if (st > 0) {
                    const uint64_t* p64 = (const uint64_t*)(H0h + (size_t)(st - 1) * 2048) + tid * 2;
                    v0 = __hip_atomic_load(p64,     __ATOMIC_RELAXED, __HIP_MEMORY_SCOPE_AGENT);
                    v1 = __hip_atomic_load(p64 + 1, __ATOMIC_RELAXED, __HIP_MEMORY_SCOPE_AGENT);
                }
                *(uint64_t*)(xh_h + tid * 8)     = v0;
                *(uint64_t*)(xh_h + tid * 8 + 4) = v1;
            }
            __syncthreads();
            #pragma unroll
            for (int b = 0; b < 4; ++b) {
                f16x8 hA = *(const f16x8*)(xh_h + b * 512 + kp * 8);
                f16x8 hB = *(const f16x8*)(xh_h + b * 512 + 256 + kp * 8);
                #pragma unroll
                for (int r = 0; r < 8; ++r) {
                    p[r][b] = dot8(wB[r][0], hA, p[r][b]);
                    p[r][b] = dot8(wB[r][1], hB, p[r][b]);
                }
            }
        } else {
            // ---- wait own group (RELAXED), stage h1[st-1], hh dots ----
            if (s > 1) {
                if (tid < 32) {
                    for (;;) {
                        int f = __hip_atomic_load(flags + (fb + tid) * 16, __ATOMIC_RELAXED,
                                                  __HIP_MEMORY_SCOPE_AGENT);
                        if (__ballot(f < s) == 0ull) break;
                        __builtin_amdgcn_s_sleep(1);
                    }
                }
                __syncthreads();
            }
            {
                uint64_t v0 = 0, v1 = 0;
                if (st > 0) {
                    const uint64_t* p64 = (const uint64_t*)(H1h + (size_t)(st - 1) * 2048) + tid * 2;
                    v0 = __hip_atomic_load(p64,     __ATOMIC_RELAXED, __HIP_MEMORY_SCOPE_AGENT);
                    v1 = __hip_atomic_load(p64 + 1, __ATOMIC_RELAXED, __HIP_MEMORY_SCOPE_AGENT);
                }
                *(uint64_t*)(xh_h + tid * 8)     = v0;
                *(uint64_t*)(xh_h + tid * 8 + 4) = v1;
            }
            __syncthreads();
            #pragma unroll
            for (int b = 0; b < 4; ++b) {
                f16x8 hA = *(const f16x8*)(xh_h + b * 512 + kp * 8);
                f16x8 hB = *(const f16x8*)(xh_h + b * 512 + 256 + kp * 8);
                #pragma unroll
                for (int r = 0; r < 8; ++r) {
                    p[r][b] = dot8(wB[r][0], hA, p[r][b]);
                    p[r][b] = dot8(wB[r][1], hB, p[r][b]);
                }
            }
            // ---- wait layer0 >= s (RELAXED), stage x = h0[st], ih dots ----
            if (tid < 32) {
                for (;;) {
                    int f = __hip_atomic_load(flags + tid * 16, __ATOMIC_RELAXED,
                                              __HIP_MEMORY_SCOPE_AGENT);
                    if (__ballot(f < s) == 0ull) break;
                    __builtin_amdgcn_s_sleep(1);
                }
            }
            __syncthreads();
            {
                const uint64_t* p64 = (const uint64_t*)(H0h + (size_t)st * 2048) + tid * 2;
                uint64_t v0 = __hip_atomic_load(p64,     __ATOMIC_RELAXED, __HIP_MEMORY_SCOPE_AGENT);
                uint64_t v1 = __hip_atomic_load(p64 + 1, __ATOMIC_RELAXED, __HIP_MEMORY_SCOPE_AGENT);
                *(uint64_t*)(xh_x + tid * 8)     = v0;
                *(uint64_t*)(xh_x + tid * 8 + 4) = v1;
            }
            __syncthreads();
            #pragma unroll
            for (int b = 0; b < 4; ++b) {
                f16x8 xA = *(const f16x8*)(xh_x + b * 512 + kp * 8);
                f16x8 xB = *(const f16x8*)(xh_x + b * 512 + 256 + kp * 8);
                #pragma unroll
                for (int r = 0; r < 8; ++r) {
                    p[r][b] = dot8(wA[r][0], xA, p[r][b]);
                    p[r][b] = dot8(wA[r][1], xB, p[r][b]);
                }
            }
        }

        // ---- butterfly reduce-scatter over 32 kp lanes: lane kp owns t=kp ----
        float a[32];
        #pragma unroll
        for (int t = 0; t < 32; ++t) a[t] = p[t >> 2][t & 3];
        #pragma unroll
        for (int m = 16; m >= 1; m >>= 1) {
            const bool hi = (kp & m) != 0;
            #pragma unroll
            for (int i = 0; i < m; ++i) {
                float give = hi ? a[i] : a[i + m];
                float got  = __shfl_xor(give, m, 64);
                a[i] = (hi ? a[i + m] : a[i]) + got;
            }
        }
        g_lds[rb_own * 4 + b_own] = a[0] + bsum;
        __syncthreads();

        // ---- activations + h/c update (wave 0 only) ----
        if (tid < 64) {
            int jj = tid >> 2, b4 = tid & 3;
            float gi = g_lds[(0  + jj) * 4 + b4];
            float gf = g_lds[(16 + jj) * 4 + b4];
            float gg = g_lds[(32 + jj) * 4 + b4];
            float go = g_lds[(48 + jj) * 4 + b4];
            c_reg = fsigm(gf) * c_reg + fsigm(gi) * ftanh(gg);
            float h2 = fsigm(go) * ftanh(c_reg);
            int hu = unit0 + jj;
            _Float16 h16 = (_Float16)h2;
            short hb;
            __builtin_memcpy(&hb, &h16, 2);
            if (!layer) {
                __hip_atomic_store((short*)(H0h + (size_t)((st << 2) + b4) * 512 + hu), hb,
                                   __ATOMIC_RELAXED, __HIP_MEMORY_SCOPE_AGENT);
            } else {
                __hip_atomic_store((short*)(H1h + (size_t)((st << 2) + b4) * 512 + hu), hb,
                                   __ATOMIC_RELAXED, __HIP_MEMORY_SCOPE_AGENT);
                __hip_atomic_store(H1 + ((size_t)(b4 * 64 + st)) * 512 + hu, h2,
                                   __ATOMIC_RELAXED, __HIP_MEMORY_SCOPE_AGENT);
            }
        }
        // release: h-stores are wave-0 write-through agent atomics; drain them
        // (vmcnt(0)), then publish the flag with a RELAXED write-through store.
        // No buffer_wbl2 / buffer_inv anywhere in the round.
        if (tid == 0) {
            asm volatile("s_waitcnt vmcnt(0)" ::: "memory");
            __hip_atomic_store(flags + blk * 16, s + 1, __ATOMIC_RELAXED,
                               __HIP_MEMORY_SCOPE_AGENT);
        }
    }
}

// ---------------------------------------------------------------------------
// small fp32 GEMM: C[m][n] = bias[n] + sum_k A[m][k]*Bt[n][k];  N=K=512.
// 64x64 tile per block; grid.x = (M/64)*8
// ---------------------------------------------------------------------------
__global__ void __launch_bounds__(256) k_gemm_small(
        const float* __restrict__ A, const float* __restrict__ Bt,
        const float* __restrict__ bias, float* __restrict__ C) {
    __shared__ float As[64 * 68];
    __shared__ float Bs[64 * 68];
    int bn = blockIdx.x & 7;
    int bm = blockIdx.x >> 3;
    int m0 = bm * 64, n0 = bn * 64;
    int tid = threadIdx.x;
    int tx = tid & 15, ty = tid >> 4;
    float acc[4][4] = {};
    for (int k0 = 0; k0 < 512; k0 += 64) {
        __syncthreads();
        #pragma unroll
        for (int i = 0; i < 4; ++i) {
            int fid = i * 256 + tid;
            int rr = fid >> 4, c4 = (fid & 15) * 4;
            *(float4*)(As + rr * 68 + c4) = *(const float4*)(A + (size_t)(m0 + rr) * 512 + k0 + c4);
            *(float4*)(Bs + rr * 68 + c4) = *(const float4*)(Bt + (size_t)(n0 + rr) * 512 + k0 + c4);
        }
        __syncthreads();
        #pragma unroll 4
        for (int kk = 0; kk < 64; kk += 4) {
            float4 a4[4], b4[4];
            #pragma unroll
            for (int ii = 0; ii < 4; ++ii) a4[ii] = *(const float4*)(As + (ty + ii * 16) * 68 + kk);
            #pragma unroll
            for (int jjx = 0; jjx < 4; ++jjx) b4[jjx] = *(const float4*)(Bs + (tx + jjx * 16) * 68 + kk);
            #pragma unroll
            for (int ii = 0; ii < 4; ++ii)
                #pragma unroll
                for (int jjx = 0; jjx < 4; ++jjx)
                    acc[ii][jjx] += a4[ii].x * b4[jjx].x + a4[ii].y * b4[jjx].y +
                                    a4[ii].z * b4[jjx].z + a4[ii].w * b4[jjx].w;
        }
    }
    #pragma unroll
    for (int ii = 0; ii < 4; ++ii) {
        int m = m0 + ty + ii * 16;
        #pragma unroll
        for (int jjx = 0; jjx < 4; ++jjx) {
            int n = n0 + tx + jjx * 16;
            float v = acc[ii][jjx] + (bias ? bias[n] : 0.f);
            C[(size_t)m * 512 + n] = v;
        }
    }
}

// ---------------------------------------------------------------------------
// joint: out[m][n] = b_out[n] + sum_k tanh(henc[b,t,k]+hdec[b,u,k]) * Wo[n][k]
// m = b*16384 + t*64 + u; M=65536, N=1024, K=512.
// 128x128 tile, BK=64, f16 MFMA 16x16x32, 4 waves 2x2, 4x4 accs each.
// ---------------------------------------------------------------------------
__global__ void __launch_bounds__(256) k_joint(
        const float* __restrict__ henc, const float* __restrict__ hdec,
        const _Float16* __restrict__ Wo, const float* __restrict__ b_out,
        float* __restrict__ out) {
    __shared__ _Float16 As[128 * 72];
    __shared__ _Float16 Bs[128 * 72];

    const int bn = blockIdx.x & 7;
    const int bm = blockIdx.x >> 3;
    const int m0 = bm * 128, n0 = bn * 128;
    const int b  = m0 >> 14;
    const int t0 = (m0 & 16383) >> 6;

    const int tid  = threadIdx.x;
    const int wave = tid >> 6, lane = tid & 63;
    const int wm = wave >> 1, wn = wave & 1;
    const int l16 = lane & 15, quad = lane >> 4;

    const int r_gen = tid >> 1;
    const int half  = tid & 1;
    const int tg = r_gen >> 6, ug = r_gen & 63;
    const float* he_row = henc + ((size_t)(b * 256 + t0 + tg)) * 512 + half * 32;
    const float* hd_row = hdec + ((size_t)(b * 64 + ug)) * 512 + half * 32;
    _Float16* As_row = As + r_gen * 72 + half * 32;

    f32x4 acc[4][4];
    #pragma unroll
    for (int i = 0; i < 4; ++i)
        #pragma unroll
        for (int jx = 0; jx < 4; ++jx) acc[i][jx] = f32x4{0.f, 0.f, 0.f, 0.f};

    for (int kit = 0; kit < 8; ++kit) {
        const int k0 = kit * 64;
        __syncthreads();
        #pragma unroll
        for (int i2 = 0; i2 < 4; ++i2) {
            float4 a  = *(const float4*)(he_row + k0 + i2 * 8);
            float4 c  = *(const float4*)(hd_row + k0 + i2 * 8);
            float4 a2 = *(const float4*)(he_row + k0 + i2 * 8 + 4);
            float4 c2 = *(const float4*)(hd_row + k0 + i2 * 8 + 4);
            f16x8 z8;
            z8[0] = (_Float16)ftanh(a.x + c.x);
            z8[1] = (_Float16)ftanh(a.y + c.y);
            z8[2] = (_Float16)ftanh(a.z + c.z);
            z8[3] = (_Float16)ftanh(a.w + c.w);
            z8[4] = (_Float16)ftanh(a2.x + c2.x);
            z8[5] = (_Float16)ftanh(a2.y + c2.y);
            z8[6] = (_Float16)ftanh(a2.z + c2.z);
            z8[7] = (_Float16)ftanh(a2.w + c2.w);
            *(f16x8*)(As_row + i2 * 8) = z8;
        }
        #pragma unroll
        for (int j2 = 0; j2 < 4; ++j2) {
            int q = j2 * 256 + tid;
            int rr = q >> 3, c8 = q & 7;
            f16x8 w = *(const f16x8*)(Wo + (size_t)(n0 + rr) * 512 + k0 + c8 * 8);
            *(f16x8*)(Bs + rr * 72 + c8 * 8) = w;
        }
        __syncthreads();
        #pragma unroll
        for (int kk = 0; kk < 64; kk += 32) {
            f16x8 af[4], bfv[4];
            #pragma unroll
            for (int i = 0; i < 4; ++i)
                af[i] = *(const f16x8*)(As + (wm * 64 + i * 16 + l16) * 72 + kk + quad * 8);
            #pragma unroll
            for (int jx = 0; jx < 4; ++jx)
                bfv[jx] = *(const f16x8*)(Bs + (wn * 64 + jx * 16 + l16) * 72 + kk + quad * 8);
            #pragma unroll
            for (int i = 0; i < 4; ++i)
                #pragma unroll
                for (int jx = 0; jx < 4; ++jx)
                    acc[i][jx] = __builtin_amdgcn_mfma_f32_16x16x32_f16(af[i], bfv[jx], acc[i][jx], 0, 0, 0);
        }
    }
    #pragma unroll
    for (int i = 0; i < 4; ++i) {
        int mrow = m0 + wm * 64 + i * 16 + quad * 4;
        #pragma unroll
        for (int jx = 0; jx < 4; ++jx) {
            int col = n0 + wn * 64 + jx * 16 + l16;
            float bo = b_out[col];
            float* po = out + (size_t)mrow * 1024 + col;
            po[0]    = acc[i][jx][0] + bo;
            po[1024] = acc[i][jx][1] + bo;
            po[2048] = acc[i][jx][2] + bo;
            po[3072] = acc[i][jx][3] + bo;
        }
    }
}

// ---------------------------------------------------------------------------
extern "C" void kernel_launch(void* const* d_in, const int* in_sizes, int n_in,
                              void* d_out, int out_size, void* d_ws, size_t ws_size,
                              hipStream_t stream) {
    const float* hs    = (const float*)d_in[0];
    const int*   ys    = (const int*)d_in[2];
    const float* embed = (const float*)d_in[3];
    const float* wih0  = (const float*)d_in[4];
    const float* whh0  = (const float*)d_in[5];
    const float* bih0  = (const float*)d_in[6];
    const float* bhh0  = (const float*)d_in[7];
    const float* wih1  = (const float*)d_in[8];
    const float* whh1  = (const float*)d_in[9];
    const float* bih1  = (const float*)d_in[10];
    const float* bhh1  = (const float*)d_in[11];
    const float* wenc  = (const float*)d_in[12];
    const float* benc  = (const float*)d_in[13];
    const float* wdec  = (const float*)d_in[14];
    const float* wout  = (const float*)d_in[15];
    const float* bout  = (const float*)d_in[16];
    float* out = (float*)d_out;

    char* ws = (char*)d_ws;
    _Float16* WF     = (_Float16*)(ws);                               // 9 MB
    _Float16* Ebuf16 = (_Float16*)(ws + 9u  * 1024 * 1024);           // 256 KB
    _Float16* H0h    = (_Float16*)(ws + 9u  * 1024 * 1024 + 512u * 1024); // 256 KB f16
    _Float16* H1h    = (_Float16*)(ws + 9u  * 1024 * 1024 + 768u * 1024); // 256 KB f16
    float* H1    = (float*)(ws + 10u * 1024 * 1024);                  // 512 KB
    float* henc  = (float*)(ws + 10u * 1024 * 1024 + 512u * 1024);    // 2 MB
    float* hdec  = (float*)(ws + 12u * 1024 * 1024 + 512u * 1024);    // 512 KB
    int*   flags = (int*)  (ws + 13u * 1024 * 1024);                  // 4 KB

    hipMemsetAsync(flags, 0, 64 * 16 * sizeof(int), stream);
    k_prep_f16<<<2048, 256, 0, stream>>>(wih0, whh0, wih1, whh1, wout, WF, 4718592);
    k_embed<<<256, 256, 0, stream>>>(embed, ys, Ebuf16);
    k_lstm<<<64, 256, 0, stream>>>(WF, bih0, bhh0, bih1, bhh1, Ebuf16, H0h, H1h, H1, flags);
    k_gemm_small<<<128, 256, 0, stream>>>(hs, wenc, benc, henc);      // M=1024
    k_gemm_small<<<32, 256, 0, stream>>>(H1, wdec, nullptr, hdec);    // M=256
    k_joint<<<4096, 256, 0, stream>>>(henc, hdec, WF + (4u << 20), bout, out);
}